// Round 13
// baseline (399.270 us; speedup 1.0000x reference)
//
#include <hip/hip_runtime.h>
#include <hip/hip_bf16.h>
#include <hip/hip_fp16.h>
#include <math.h>

#define N_NODES 20000
#define N_EDGES 320000
#define IN_FEAT 128
#define HIDDEN 256
#define OUT_DIM 12
#define NUM_SCALES 5
#define NUM_CONVS 3
#define NUM_GRAPHS 800
#define BN_EPS 1e-5f
#define M_PAD 20096  // 157 * 128

#define COLBLK 64
#define NCB (HIDDEN / COLBLK)            // 4
#define VPB 32                           // nodes per block in gather (4 waves x 8 groups)
#define BPC (N_NODES / VPB)              // 625 blocks per combo

typedef __attribute__((ext_vector_type(8))) short bf16x8;
typedef __attribute__((ext_vector_type(4))) float f32x4;
typedef __attribute__((ext_vector_type(2))) float f32x2;

__device__ __forceinline__ float bf2f(unsigned short u) {
    return __uint_as_float((unsigned)u << 16);
}
__device__ __forceinline__ unsigned short f2bf(float x) {
    unsigned u = __float_as_uint(x);
    return (unsigned short)((u + 0x7fffu + ((u >> 16) & 1u)) >> 16);
}
__device__ __forceinline__ void load_lds16(const void* g, void* l) {
    __builtin_amdgcn_global_load_lds(
        (const __attribute__((address_space(1))) unsigned int*)g,
        (__attribute__((address_space(3))) unsigned int*)l, 16, 0, 0);
}

// ---------------- degree histogram ----------------
__global__ void hist_kernel(const int* __restrict__ dst, int* __restrict__ cnt) {
    int e = blockIdx.x * blockDim.x + threadIdx.x;
    if (e < N_EDGES) atomicAdd(&cnt[dst[e]], 1);
}

// LDS-hist degree histogram
__global__ void deg_hist_kernel(const int* __restrict__ cnt, int* __restrict__ dhist) {
    __shared__ int lh[128];
    int t = threadIdx.x;
    if (t < 128) lh[t] = 0;
    __syncthreads();
    int v = blockIdx.x * 256 + t;
    if (v < N_NODES) atomicAdd(&lh[min(cnt[v], 127)], 1);
    __syncthreads();
    if (t < 128 && lh[t]) atomicAdd(&dhist[t], lh[t]);
}
__global__ void deg_scan_kernel(const int* __restrict__ dhist, int* __restrict__ doff) {
    __shared__ int s[128];
    int t = threadIdx.x;
    s[t] = dhist[t];
    __syncthreads();
    if (t == 0) {
        int acc = 0;
        for (int x = 0; x < 128; ++x) { int c = s[x]; s[x] = acc; acc += c; }
    }
    __syncthreads();
    doff[t] = s[t];
}
// places nodes into perm; writes degp at permuted pos AND pinv in one pass
__global__ void deg_place_kernel(const int* __restrict__ cnt, int* __restrict__ doff,
                                 int* __restrict__ perm, int* __restrict__ degp,
                                 int* __restrict__ pinv) {
    __shared__ int lhist[128];
    __shared__ int lbase[128];
    const int t = threadIdx.x;
    if (t < 128) lhist[t] = 0;
    __syncthreads();
    const int v = blockIdx.x * 256 + t;
    int d = 0, bin = 0, lrank = 0;
    const bool valid = (v < N_NODES);
    if (valid) {
        d = cnt[v];
        bin = min(d, 127);
        lrank = atomicAdd(&lhist[bin], 1);
    }
    __syncthreads();
    if (t < 128 && lhist[t] > 0) lbase[t] = atomicAdd(&doff[t], lhist[t]);
    __syncthreads();
    if (valid) {
        int pos = lbase[bin] + lrank;
        perm[pos] = v;
        degp[pos] = d;
        pinv[v] = pos;
    }
}

// ---------------- row_ptr & normp over PERMUTED node order (sequential degp reads) ----------------
__global__ void scanp_kernel(const int* __restrict__ degp,
                             int* __restrict__ row_ptr, float* __restrict__ normp) {
    __shared__ int wsum[16];
    const int tid = threadIdx.x;
    const int wave = tid >> 6, lane = tid & 63;
    int running = 0;
    const int NCHUNK = (N_NODES + 1023) / 1024;
    for (int c = 0; c < NCHUNK; ++c) {
        const int i = c * 1024 + tid;
        int v = 0;
        if (i < N_NODES) {
            v = degp[i];
            normp[i] = rsqrtf(fmaxf((float)v, 1.0f));
        }
        int x = v;
#pragma unroll
        for (int off = 1; off < 64; off <<= 1) {
            int y = __shfl_up(x, off, 64);
            if (lane >= off) x += y;
        }
        if (lane == 63) wsum[wave] = x;
        __syncthreads();
        if (wave == 0) {
            int w = (lane < 16) ? wsum[lane] : 0;
#pragma unroll
            for (int off = 1; off < 16; off <<= 1) {
                int y = __shfl_up(w, off, 64);
                if (lane >= off) w += y;
            }
            if (lane < 16) wsum[lane] = w;
        }
        __syncthreads();
        const int prefix = (wave > 0) ? wsum[wave - 1] : 0;
        x += prefix + running;
        if (i < N_NODES) row_ptr[i + 1] = x;
        running += wsum[15];
        __syncthreads();
    }
    if (tid == 0) row_ptr[0] = 0;
}

// ---------------- edge scatter into permuted CSR; entry = pre-shifted byte offset pinv(src)<<9 ----------------
__global__ void scatter_kernel(const int* __restrict__ src, const int* __restrict__ dst,
                               const int* __restrict__ row_ptr, int* __restrict__ cursor,
                               const int* __restrict__ pinv,
                               unsigned* __restrict__ edge_pack) {
    int e = blockIdx.x * blockDim.x + threadIdx.x;
    if (e < N_EDGES) {
        int dp = pinv[dst[e]];
        int u = src[e];
        int pos = atomicAdd(&cursor[dp], 1);
        edge_pack[row_ptr[dp] + pos] = (unsigned)pinv[u] << 9;
    }
}

__global__ void graph_start_kernel(const int* __restrict__ gid, int* __restrict__ gstart) {
    int i = blockIdx.x * blockDim.x + threadIdx.x;
    if (i >= N_NODES) return;
    int g = gid[i];
    if (i == 0) {
        for (int x = 0; x <= g; ++x) gstart[x] = 0;
    } else {
        int gp = gid[i - 1];
        for (int x = gp + 1; x <= g; ++x) gstart[x] = i;
    }
    if (i == N_NODES - 1) {
        for (int x = g + 1; x <= NUM_GRAPHS; ++x) gstart[x] = N_NODES;
    }
}

// ---------------- small prep kernels ----------------
__global__ void bn_precompute(const float* __restrict__ g, const float* __restrict__ b,
                              const float* __restrict__ m, const float* __restrict__ v,
                              float* __restrict__ scale, float* __restrict__ shift) {
    int i = blockIdx.x * 256 + threadIdx.x;
    float sc = g[i] * rsqrtf(v[i] + BN_EPS);
    scale[i] = sc;
    shift[i] = b[i] - m[i] * sc;
}

// features f32 [N][128] -> bf16 [M_PAD][128] in PERMUTED row order
__global__ void feat_convert(const float* __restrict__ f, const int* __restrict__ perm,
                             unsigned short* __restrict__ o) {
    int i = blockIdx.x * 256 + threadIdx.x;
    int e0 = i * 4;
    int r = e0 >> 7, c = e0 & 127;
    float4 v = make_float4(0.f, 0.f, 0.f, 0.f);
    if (r < N_NODES) {
        int pr = perm[r];
        v = *reinterpret_cast<const float4*>(&f[(size_t)pr * IN_FEAT + c]);
    }
    ushort4 u;
    u.x = f2bf(v.x); u.y = f2bf(v.y); u.z = f2bf(v.z); u.w = f2bf(v.w);
    *reinterpret_cast<ushort4*>(&o[e0]) = u;
}

__global__ void transpose_bf16(const float* __restrict__ in, unsigned short* __restrict__ out,
                               int K, int N) {
    __shared__ float tile[32][33];
    const int b = blockIdx.z;
    in += (size_t)b * K * N;
    out += (size_t)b * K * N;
    const int k0 = blockIdx.x * 32, n0 = blockIdx.y * 32;
    for (int i = threadIdx.y; i < 32; i += 8)
        tile[i][threadIdx.x] = in[(size_t)(k0 + i) * N + n0 + threadIdx.x];
    __syncthreads();
    for (int i = threadIdx.y; i < 32; i += 8)
        out[(size_t)(n0 + i) * K + k0 + threadIdx.x] = f2bf(tile[threadIdx.x][i]);
}

// ---------------- XCD-steered, balanced, degree-sorted gather (perm space) ----------------
// h buffer holds hn = normp ⊙ h (norm folded into GEMM epilogue): pure bf16 row-sum loop.
// Edge word = pre-shifted byte offset. XCD k owns w in [k*nwu/8,(k+1)*nwu/8); per-XCD live
// set = h slice 2.56MB + edges 1.28MB < 4MB L2. SNAKE j-map inside each combo equalizes
// per-XCD edge counts (contiguous u-ranges carry average degree density).
__device__ __forceinline__ void accum8(f32x2* a, uint4 r) {
    const unsigned* u = reinterpret_cast<const unsigned*>(&r);
#pragma unroll
    for (int q = 0; q < 4; ++q) {
        f32x2 t;
        t.x = __uint_as_float(u[q] << 16);
        t.y = __uint_as_float(u[q] & 0xffff0000u);
        a[q] += t;   // v_pk_add_f32
    }
}

__global__ __launch_bounds__(256) void gather_cb(
    const unsigned short* __restrict__ h, size_t h_zstride,
    const float* __restrict__ normp,
    const int* __restrict__ row_ptr, const unsigned* __restrict__ edge_pack,
    unsigned short* __restrict__ agg, size_t a_zstride, int nwu) {
    const int k = blockIdx.x & 7;
    const int bi = blockIdx.x >> 3;
    const int start = (k * nwu) >> 3;
    const int end = ((k + 1) * nwu) >> 3;
    const int w = start + bi;
    if (w >= end) return;
    const int combo = w / BPC;
    const int u0 = w - combo * BPC;
    // snake: even u -> low half ascending, odd u -> high half descending
    const int j = (u0 & 1) ? (BPC - 1 - (u0 >> 1)) : (u0 >> 1);
    const int s = combo >> 2;   // NCB == 4
    const int cb = combo & 3;
    const int lane = threadIdx.x & 63, wave = threadIdx.x >> 6;
    const int grp = lane >> 3;          // 0..7: node within wave
    const int lc = lane & 7;            // lane within group
    const char* __restrict__ hbb =
        (const char*)h + ((size_t)s * h_zstride + cb * COLBLK + lc * 8) * 2;
    const int p = j * VPB + wave * 8 + grp;   // permuted node id
    const int beg = row_ptr[p], end_e = row_ptr[p + 1];
    const float nv = normp[p];
    const unsigned* __restrict__ ep = edge_pack + beg;
    const int n = end_e - beg;
    f32x2 a[4] = {};
    int i = 0;
    for (; i + 7 < n; i += 8) {
        unsigned e[8];
        uint4 r[8];
#pragma unroll
        for (int q = 0; q < 8; ++q) e[q] = ep[i + q];
#pragma unroll
        for (int q = 0; q < 8; ++q)
            r[q] = *reinterpret_cast<const uint4*>(hbb + e[q]);
#pragma unroll
        for (int q = 0; q < 8; ++q) accum8(a, r[q]);
    }
    for (; i + 3 < n; i += 4) {
        unsigned e[4];
        uint4 r[4];
#pragma unroll
        for (int q = 0; q < 4; ++q) e[q] = ep[i + q];
#pragma unroll
        for (int q = 0; q < 4; ++q)
            r[q] = *reinterpret_cast<const uint4*>(hbb + e[q]);
#pragma unroll
        for (int q = 0; q < 4; ++q) accum8(a, r[q]);
    }
    for (; i < n; ++i) {
        const uint4 r0 = *reinterpret_cast<const uint4*>(hbb + ep[i]);
        accum8(a, r0);
    }
    uint4 o;
    unsigned* ou = reinterpret_cast<unsigned*>(&o);
#pragma unroll
    for (int q = 0; q < 4; ++q) {
        unsigned lo = f2bf(nv * a[q].x);
        unsigned hi = f2bf(nv * a[q].y);
        ou[q] = lo | (hi << 16);
    }
    *reinterpret_cast<uint4*>(
        &agg[(size_t)s * a_zstride + (size_t)p * HIDDEN + cb * COLBLK + lc * 8]) = o;
}

// ---------------- MFMA GEMM: C[M_PAD x 256] = A[M_PAD x K] @ Bt^T ----------------
// optional BN+ReLU; optional rowscale (writes hn = normp ⊙ result for gather consumption)
template <int K, bool BNRELU, bool RS>
__global__ __launch_bounds__(256, 3) void mfma_gemm(
    const unsigned short* __restrict__ A, size_t a_zstride,
    const unsigned short* __restrict__ Bt, size_t b_zstride,
    unsigned short* __restrict__ C, size_t c_zstride,
    const float* __restrict__ bn_scale, const float* __restrict__ bn_shift, int bn_zstride,
    const float* __restrict__ rowscale) {
    constexpr int BK = 64;
    __shared__ __align__(16) unsigned short As[128 * BK];
    __shared__ __align__(16) unsigned short Bs[128 * BK];
    const int z = blockIdx.z;
    A += (size_t)z * a_zstride;
    Bt += (size_t)z * b_zstride;
    C += (size_t)z * c_zstride;
    const int tid = threadIdx.x, lane = tid & 63, wave = tid >> 6;
    const int wr = wave >> 1, wc = wave & 1;
    const int r0 = blockIdx.x * 128, c0 = blockIdx.y * 128;

    const int lrow = lane >> 3;
    const int kch = (lane & 7) ^ lrow;
    const int frow = lane & 15;
    const int kgrp = lane >> 4;

    f32x4 acc[4][4];
#pragma unroll
    for (int i = 0; i < 4; ++i)
#pragma unroll
        for (int j = 0; j < 4; ++j) acc[i][j] = (f32x4)0.f;

    int aoff[4][2], boff[4][2];
#pragma unroll
    for (int fm = 0; fm < 4; ++fm) {
        const int ra = wr * 64 + fm * 16 + frow;
        const int rb = wc * 64 + fm * 16 + frow;
#pragma unroll
        for (int ks = 0; ks < 2; ++ks) {
            aoff[fm][ks] = ra * 64 + ((ks * 4 + kgrp) ^ (ra & 7)) * 8;
            boff[fm][ks] = rb * 64 + ((ks * 4 + kgrp) ^ (rb & 7)) * 8;
        }
    }

    constexpr int NK = K / BK;
#pragma unroll
    for (int k0 = 0; k0 < NK; ++k0) {
        const int kk = k0 * BK;
#pragma unroll
        for (int i = 0; i < 4; ++i) {
            const int tb = wave * 32 + i * 8;
            load_lds16(&A[(size_t)(r0 + tb + lrow) * K + kk + kch * 8], &As[tb * 64]);
            load_lds16(&Bt[(size_t)(c0 + tb + lrow) * K + kk + kch * 8], &Bs[tb * 64]);
        }
        __syncthreads();
#pragma unroll
        for (int ks = 0; ks < 2; ++ks) {
            bf16x8 af[4], bfr[4];
#pragma unroll
            for (int fm = 0; fm < 4; ++fm) af[fm] = *reinterpret_cast<const bf16x8*>(&As[aoff[fm][ks]]);
#pragma unroll
            for (int fn = 0; fn < 4; ++fn) bfr[fn] = *reinterpret_cast<const bf16x8*>(&Bs[boff[fn][ks]]);
#pragma unroll
            for (int fm = 0; fm < 4; ++fm)
#pragma unroll
                for (int fn = 0; fn < 4; ++fn)
                    acc[fm][fn] = __builtin_amdgcn_mfma_f32_16x16x32_bf16(af[fm], bfr[fn], acc[fm][fn], 0, 0, 0);
        }
        __syncthreads();
    }

    float rsv[4][4];
    if (RS) {
#pragma unroll
        for (int fm = 0; fm < 4; ++fm) {
            const int rbase = r0 + wr * 64 + fm * 16 + kgrp * 4;
#pragma unroll
            for (int r = 0; r < 4; ++r) rsv[fm][r] = rowscale[rbase + r];
        }
    }

#pragma unroll
    for (int fn = 0; fn < 4; ++fn) {
        const int col = c0 + wc * 64 + fn * 16 + frow;
        float sc = 1.f, sh = 0.f;
        if (BNRELU) {
            sc = bn_scale[z * bn_zstride + col];
            sh = bn_shift[z * bn_zstride + col];
        }
#pragma unroll
        for (int fm = 0; fm < 4; ++fm) {
            const int rbase = r0 + wr * 64 + fm * 16 + kgrp * 4;
#pragma unroll
            for (int r = 0; r < 4; ++r) {
                float x = acc[fm][fn][r];
                if (BNRELU) x = fmaxf(x * sc + sh, 0.f);
                if (RS) x *= rsv[fm][r];
                C[(size_t)(rbase + r) * HIDDEN + col] = f2bf(x);
            }
        }
    }
}

// ---------------- per-graph mean pool (h rows in permuted order -> pinv lookup) ----------------
__global__ __launch_bounds__(256) void pool_kernel(
    const unsigned short* __restrict__ h, size_t h_zstride,
    const int* __restrict__ pinv,
    const int* __restrict__ gstart, float* __restrict__ pool, int s0) {
    const int g = blockIdx.x, c = threadIdx.x;
    const int s = s0 + blockIdx.y;
    const unsigned short* hb = h + (size_t)blockIdx.y * h_zstride;
    const int beg = gstart[g], end = gstart[g + 1];
    float acc = 0.f;
    for (int v = beg; v < end; ++v) {
        int p = pinv[v];
        acc += bf2f(hb[(size_t)p * HIDDEN + c]);
    }
    pool[((size_t)s * NUM_GRAPHS + g) * HIDDEN + c] = acc / fmaxf((float)(end - beg), 1.f);
}

// ---------------- final MLP ----------------
__global__ __launch_bounds__(256) void final_kernel(
    const float* __restrict__ pool,
    const float* __restrict__ W_fc1, const float* __restrict__ b_fc1,
    const float* __restrict__ W_out, const float* __restrict__ b_out,
    float* __restrict__ out) {
    __shared__ float hv[HIDDEN];
    __shared__ float h1[HIDDEN];
    __shared__ float red[HIDDEN];
    const int g = blockIdx.x, t = threadIdx.x;
    float x = 0.f;
#pragma unroll
    for (int s = 0; s < NUM_SCALES; ++s) x += pool[((size_t)s * NUM_GRAPHS + g) * HIDDEN + t];
    x *= (1.0f / NUM_SCALES);
    red[t] = x * x;
    __syncthreads();
    for (int off = 128; off > 0; off >>= 1) {
        if (t < off) red[t] += red[t + off];
        __syncthreads();
    }
    float inv = 1.0f / fmaxf(sqrtf(red[0]), 1e-12f);
    hv[t] = x * inv;
    __syncthreads();
    float acc = b_fc1[t];
    for (int k = 0; k < HIDDEN; ++k) acc += hv[k] * W_fc1[k * HIDDEN + t];
    h1[t] = (acc > 0.f) ? acc : 0.01f * acc;
    __syncthreads();
    if (t < OUT_DIM) {
        float o = b_out[t];
        for (int k = 0; k < HIDDEN; ++k) o += h1[k] * W_out[k * OUT_DIM + t];
        out[g * OUT_DIM + t] = 1.0f / (1.0f + expf(-o));
    }
}

extern "C" void kernel_launch(void* const* d_in, const int* in_sizes, int n_in,
                              void* d_out, int out_size, void* d_ws, size_t ws_size,
                              hipStream_t stream) {
    const float* features  = (const float*)d_in[0];
    const int*   src       = (const int*)d_in[1];
    const int*   dst       = (const int*)d_in[2];
    const int*   graph_ids = (const int*)d_in[3];
    const float* W_proj   = (const float*)d_in[5];
    const float* W_conv   = (const float*)d_in[6];
    const float* bn_gamma = (const float*)d_in[7];
    const float* bn_beta  = (const float*)d_in[8];
    const float* bn_mean  = (const float*)d_in[9];
    const float* bn_var   = (const float*)d_in[10];
    const float* W_fc1    = (const float*)d_in[11];
    const float* b_fc1    = (const float*)d_in[12];
    const float* W_out    = (const float*)d_in[13];
    const float* b_out    = (const float*)d_in[14];
    float* out = (float*)d_out;

    size_t off = 0;
    char* base = (char*)d_ws;
    auto alloc = [&](size_t bytes) -> void* {
        void* p = base + off;
        off += (bytes + 255) & ~(size_t)255;
        return p;
    };
    int*   cnt       = (int*)alloc(N_NODES * 4);
    float* normp     = (float*)alloc(N_NODES * 4);
    int*   row_ptr   = (int*)alloc((N_NODES + 1) * 4);
    int*   cursor    = (int*)alloc(N_NODES * 4);
    unsigned* edge_pack = (unsigned*)alloc((size_t)N_EDGES * 4);
    int*   gstart    = (int*)alloc((NUM_GRAPHS + 1) * 4);
    int*   dhist     = (int*)alloc(128 * 4);
    int*   doff      = (int*)alloc(128 * 4);
    int*   perm      = (int*)alloc(N_NODES * 4);
    int*   pinv      = (int*)alloc(N_NODES * 4);
    int*   degp      = (int*)alloc(N_NODES * 4);
    float* bn_scale  = (float*)alloc(NUM_SCALES * NUM_CONVS * HIDDEN * 4);
    float* bn_shift  = (float*)alloc(NUM_SCALES * NUM_CONVS * HIDDEN * 4);
    unsigned short* feat_b  = (unsigned short*)alloc((size_t)M_PAD * IN_FEAT * 2);
    unsigned short* Wt_proj = (unsigned short*)alloc((size_t)NUM_SCALES * HIDDEN * IN_FEAT * 2);
    unsigned short* Wt_conv = (unsigned short*)alloc((size_t)NUM_SCALES * NUM_CONVS * HIDDEN * HIDDEN * 2);
    float* pool      = (float*)alloc((size_t)NUM_SCALES * NUM_GRAPHS * HIDDEN * 4);

    const size_t HSZ = (size_t)M_PAD * HIDDEN;
    const bool batched = (ws_size - off) >= (2 * NUM_SCALES * HSZ * 2 + 1024);
    const int nsb = batched ? NUM_SCALES : 1;
    unsigned short* h_all   = (unsigned short*)alloc((size_t)nsb * HSZ * 2);
    unsigned short* agg_all = (unsigned short*)alloc((size_t)nsb * HSZ * 2);

    // ---- setup: degrees, degree-sort perm, permuted CSR ----
    hipMemsetAsync(cnt, 0, N_NODES * sizeof(int), stream);
    hipMemsetAsync(dhist, 0, 128 * sizeof(int), stream);
    hist_kernel<<<(N_EDGES + 255) / 256, 256, 0, stream>>>(dst, cnt);
    deg_hist_kernel<<<(N_NODES + 255) / 256, 256, 0, stream>>>(cnt, dhist);
    deg_scan_kernel<<<1, 128, 0, stream>>>(dhist, doff);
    deg_place_kernel<<<(N_NODES + 255) / 256, 256, 0, stream>>>(cnt, doff, perm, degp, pinv);
    scanp_kernel<<<1, 1024, 0, stream>>>(degp, row_ptr, normp);
    hipMemsetAsync(cursor, 0, N_NODES * sizeof(int), stream);
    scatter_kernel<<<(N_EDGES + 255) / 256, 256, 0, stream>>>(
        src, dst, row_ptr, cursor, pinv, edge_pack);
    graph_start_kernel<<<(N_NODES + 255) / 256, 256, 0, stream>>>(graph_ids, gstart);
    bn_precompute<<<NUM_SCALES * NUM_CONVS, 256, 0, stream>>>(bn_gamma, bn_beta, bn_mean, bn_var,
                                                              bn_scale, bn_shift);
    feat_convert<<<(M_PAD * IN_FEAT / 4 + 255) / 256, 256, 0, stream>>>(features, perm, feat_b);
    transpose_bf16<<<dim3(IN_FEAT / 32, HIDDEN / 32, NUM_SCALES), dim3(32, 8), 0, stream>>>(
        W_proj, Wt_proj, IN_FEAT, HIDDEN);
    transpose_bf16<<<dim3(HIDDEN / 32, HIDDEN / 32, NUM_SCALES * NUM_CONVS), dim3(32, 8), 0, stream>>>(
        W_conv, Wt_conv, HIDDEN, HIDDEN);

    const int MT = M_PAD / 128;  // 157
    if (batched) {
        const int nwu = NUM_SCALES * NCB * BPC;              // 12500
        const int ggrid = 8 * ((nwu + 7) / 8);               // 12504
        // proj writes hn0 = normp ⊙ (feat @ Wproj)
        mfma_gemm<IN_FEAT, false, true><<<dim3(MT, 2, NUM_SCALES), 256, 0, stream>>>(
            feat_b, 0, Wt_proj, (size_t)HIDDEN * IN_FEAT, h_all, HSZ, nullptr, nullptr, 0, normp);
        for (int i = 0; i < NUM_CONVS; ++i) {
            gather_cb<<<ggrid, 256, 0, stream>>>(
                h_all, HSZ, normp, row_ptr, edge_pack, agg_all, HSZ, nwu);
            if (i < NUM_CONVS - 1) {
                mfma_gemm<HIDDEN, true, true><<<dim3(MT, 2, NUM_SCALES), 256, 0, stream>>>(
                    agg_all, HSZ, Wt_conv + (size_t)i * HIDDEN * HIDDEN, (size_t)NUM_CONVS * HIDDEN * HIDDEN,
                    h_all, HSZ, bn_scale + i * HIDDEN, bn_shift + i * HIDDEN, NUM_CONVS * HIDDEN, normp);
            } else {
                mfma_gemm<HIDDEN, true, false><<<dim3(MT, 2, NUM_SCALES), 256, 0, stream>>>(
                    agg_all, HSZ, Wt_conv + (size_t)i * HIDDEN * HIDDEN, (size_t)NUM_CONVS * HIDDEN * HIDDEN,
                    h_all, HSZ, bn_scale + i * HIDDEN, bn_shift + i * HIDDEN, NUM_CONVS * HIDDEN, nullptr);
            }
        }
        pool_kernel<<<dim3(NUM_GRAPHS, NUM_SCALES), 256, 0, stream>>>(
            h_all, HSZ, pinv, gstart, pool, 0);
    } else {
        const int nwu = NCB * BPC;                           // 2500
        const int ggrid = 8 * ((nwu + 7) / 8);
        for (int s = 0; s < NUM_SCALES; ++s) {
            mfma_gemm<IN_FEAT, false, true><<<dim3(MT, 2, 1), 256, 0, stream>>>(
                feat_b, 0, Wt_proj + (size_t)s * HIDDEN * IN_FEAT, 0, h_all, 0, nullptr, nullptr, 0, normp);
            for (int i = 0; i < NUM_CONVS; ++i) {
                const size_t li = (size_t)(s * NUM_CONVS + i);
                gather_cb<<<ggrid, 256, 0, stream>>>(
                    h_all, 0, normp, row_ptr, edge_pack, agg_all, 0, nwu);
                if (i < NUM_CONVS - 1) {
                    mfma_gemm<HIDDEN, true, true><<<dim3(MT, 2, 1), 256, 0, stream>>>(
                        agg_all, 0, Wt_conv + li * HIDDEN * HIDDEN, 0, h_all, 0,
                        bn_scale + li * HIDDEN, bn_shift + li * HIDDEN, 0, normp);
                } else {
                    mfma_gemm<HIDDEN, true, false><<<dim3(MT, 2, 1), 256, 0, stream>>>(
                        agg_all, 0, Wt_conv + li * HIDDEN * HIDDEN, 0, h_all, 0,
                        bn_scale + li * HIDDEN, bn_shift + li * HIDDEN, 0, nullptr);
                }
            }
            pool_kernel<<<dim3(NUM_GRAPHS, 1), 256, 0, stream>>>(
                h_all, 0, pinv, gstart, pool, s);
        }
    }
    final_kernel<<<NUM_GRAPHS, 256, 0, stream>>>(pool, W_fc1, b_fc1, W_out, b_out, out);
}

// Round 14
// 385.799 us; speedup vs baseline: 1.0349x; 1.0349x over previous
//
#include <hip/hip_runtime.h>
#include <hip/hip_bf16.h>
#include <hip/hip_fp16.h>
#include <math.h>

#define N_NODES 20000
#define N_EDGES 320000
#define IN_FEAT 128
#define HIDDEN 256
#define OUT_DIM 12
#define NUM_SCALES 5
#define NUM_CONVS 3
#define NUM_GRAPHS 800
#define BN_EPS 1e-5f
#define M_PAD 20096  // 157 * 128

#define COLBLK 64
#define NCB (HIDDEN / COLBLK)            // 4
#define VPB 32                           // nodes per block in gather (4 waves x 8 groups)
#define BPC (N_NODES / VPB)              // 625 blocks per combo

typedef __attribute__((ext_vector_type(8))) short bf16x8;
typedef __attribute__((ext_vector_type(4))) float f32x4;
typedef __attribute__((ext_vector_type(2))) float f32x2;

__device__ __forceinline__ float bf2f(unsigned short u) {
    return __uint_as_float((unsigned)u << 16);
}
__device__ __forceinline__ unsigned short f2bf(float x) {
    unsigned u = __float_as_uint(x);
    return (unsigned short)((u + 0x7fffu + ((u >> 16) & 1u)) >> 16);
}
__device__ __forceinline__ void load_lds16(const void* g, void* l) {
    __builtin_amdgcn_global_load_lds(
        (const __attribute__((address_space(1))) unsigned int*)g,
        (__attribute__((address_space(3))) unsigned int*)l, 16, 0, 0);
}

// ---------------- degree histogram ----------------
__global__ void hist_kernel(const int* __restrict__ dst, int* __restrict__ cnt) {
    int e = blockIdx.x * blockDim.x + threadIdx.x;
    if (e < N_EDGES) atomicAdd(&cnt[dst[e]], 1);
}

// LDS-hist degree histogram
__global__ void deg_hist_kernel(const int* __restrict__ cnt, int* __restrict__ dhist) {
    __shared__ int lh[128];
    int t = threadIdx.x;
    if (t < 128) lh[t] = 0;
    __syncthreads();
    int v = blockIdx.x * 256 + t;
    if (v < N_NODES) atomicAdd(&lh[min(cnt[v], 127)], 1);
    __syncthreads();
    if (t < 128 && lh[t]) atomicAdd(&dhist[t], lh[t]);
}

// places nodes into perm; in-block exclusive scan of dhist replaces the separate scan
// kernel (bincur is a zero-init global per-bin cursor). Writes degp at permuted pos AND pinv.
__global__ void deg_place_kernel(const int* __restrict__ cnt, const int* __restrict__ dhist,
                                 int* __restrict__ bincur,
                                 int* __restrict__ perm, int* __restrict__ degp,
                                 int* __restrict__ pinv) {
    __shared__ int sbase[128];
    __shared__ int lhist[128];
    __shared__ int lbase[128];
    const int t = threadIdx.x;
    if (t < 128) lhist[t] = 0;
    if (t == 0) {
        int acc = 0;
        for (int x = 0; x < 128; ++x) { sbase[x] = acc; acc += dhist[x]; }
    }
    __syncthreads();
    const int v = blockIdx.x * 256 + t;
    int d = 0, bin = 0, lrank = 0;
    const bool valid = (v < N_NODES);
    if (valid) {
        d = cnt[v];
        bin = min(d, 127);
        lrank = atomicAdd(&lhist[bin], 1);
    }
    __syncthreads();
    if (t < 128 && lhist[t] > 0) lbase[t] = sbase[t] + atomicAdd(&bincur[t], lhist[t]);
    __syncthreads();
    if (valid) {
        int pos = lbase[bin] + lrank;
        perm[pos] = v;
        degp[pos] = d;
        pinv[v] = pos;
    }
}

// ---------------- row_ptr & normp over PERMUTED node order (sequential degp reads) ----------------
__global__ void scanp_kernel(const int* __restrict__ degp,
                             int* __restrict__ row_ptr, float* __restrict__ normp) {
    __shared__ int wsum[16];
    const int tid = threadIdx.x;
    const int wave = tid >> 6, lane = tid & 63;
    int running = 0;
    const int NCHUNK = (N_NODES + 1023) / 1024;
    for (int c = 0; c < NCHUNK; ++c) {
        const int i = c * 1024 + tid;
        int v = 0;
        if (i < N_NODES) {
            v = degp[i];
            normp[i] = rsqrtf(fmaxf((float)v, 1.0f));
        }
        int x = v;
#pragma unroll
        for (int off = 1; off < 64; off <<= 1) {
            int y = __shfl_up(x, off, 64);
            if (lane >= off) x += y;
        }
        if (lane == 63) wsum[wave] = x;
        __syncthreads();
        if (wave == 0) {
            int w = (lane < 16) ? wsum[lane] : 0;
#pragma unroll
            for (int off = 1; off < 16; off <<= 1) {
                int y = __shfl_up(w, off, 64);
                if (lane >= off) w += y;
            }
            if (lane < 16) wsum[lane] = w;
        }
        __syncthreads();
        const int prefix = (wave > 0) ? wsum[wave - 1] : 0;
        x += prefix + running;
        if (i < N_NODES) row_ptr[i + 1] = x;
        running += wsum[15];
        __syncthreads();
    }
    if (tid == 0) row_ptr[0] = 0;
}

// ---------------- edge scatter into permuted CSR; entry = pre-shifted byte offset pinv(src)<<9 ----------------
__global__ void scatter_kernel(const int* __restrict__ src, const int* __restrict__ dst,
                               const int* __restrict__ row_ptr, int* __restrict__ cursor,
                               const int* __restrict__ pinv,
                               unsigned* __restrict__ edge_pack) {
    int e = blockIdx.x * blockDim.x + threadIdx.x;
    if (e < N_EDGES) {
        int dp = pinv[dst[e]];
        int u = src[e];
        int pos = atomicAdd(&cursor[dp], 1);
        edge_pack[row_ptr[dp] + pos] = (unsigned)pinv[u] << 9;
    }
}

__global__ void graph_start_kernel(const int* __restrict__ gid, int* __restrict__ gstart) {
    int i = blockIdx.x * blockDim.x + threadIdx.x;
    if (i >= N_NODES) return;
    int g = gid[i];
    if (i == 0) {
        for (int x = 0; x <= g; ++x) gstart[x] = 0;
    } else {
        int gp = gid[i - 1];
        for (int x = gp + 1; x <= g; ++x) gstart[x] = i;
    }
    if (i == N_NODES - 1) {
        for (int x = g + 1; x <= NUM_GRAPHS; ++x) gstart[x] = N_NODES;
    }
}

// ---------------- small prep kernels ----------------
__global__ void bn_precompute(const float* __restrict__ g, const float* __restrict__ b,
                              const float* __restrict__ m, const float* __restrict__ v,
                              float* __restrict__ scale, float* __restrict__ shift) {
    int i = blockIdx.x * 256 + threadIdx.x;
    float sc = g[i] * rsqrtf(v[i] + BN_EPS);
    scale[i] = sc;
    shift[i] = b[i] - m[i] * sc;
}

// features f32 [N][128] -> bf16 [M_PAD][128] in PERMUTED row order
__global__ void feat_convert(const float* __restrict__ f, const int* __restrict__ perm,
                             unsigned short* __restrict__ o) {
    int i = blockIdx.x * 256 + threadIdx.x;
    int e0 = i * 4;
    int r = e0 >> 7, c = e0 & 127;
    float4 v = make_float4(0.f, 0.f, 0.f, 0.f);
    if (r < N_NODES) {
        int pr = perm[r];
        v = *reinterpret_cast<const float4*>(&f[(size_t)pr * IN_FEAT + c]);
    }
    ushort4 u;
    u.x = f2bf(v.x); u.y = f2bf(v.y); u.z = f2bf(v.z); u.w = f2bf(v.w);
    *reinterpret_cast<ushort4*>(&o[e0]) = u;
}

__global__ void transpose_bf16(const float* __restrict__ in, unsigned short* __restrict__ out,
                               int K, int N) {
    __shared__ float tile[32][33];
    const int b = blockIdx.z;
    in += (size_t)b * K * N;
    out += (size_t)b * K * N;
    const int k0 = blockIdx.x * 32, n0 = blockIdx.y * 32;
    for (int i = threadIdx.y; i < 32; i += 8)
        tile[i][threadIdx.x] = in[(size_t)(k0 + i) * N + n0 + threadIdx.x];
    __syncthreads();
    for (int i = threadIdx.y; i < 32; i += 8)
        out[(size_t)(n0 + i) * K + k0 + threadIdx.x] = f2bf(tile[threadIdx.x][i]);
}

// ---------------- XCD-steered, balanced, degree-sorted gather (perm space) ----------------
// h buffer holds hn = normp ⊙ h (norm folded into GEMM epilogue): pure bf16 row-sum loop.
// Edge word = pre-shifted byte offset. XCD k owns w in [k*nwu/8,(k+1)*nwu/8); per-XCD live
// set = h slice 2.56MB + edges 1.28MB < 4MB L2. Linear j map (snake regressed, r13).
__device__ __forceinline__ void accum8(f32x2* a, uint4 r) {
    const unsigned* u = reinterpret_cast<const unsigned*>(&r);
#pragma unroll
    for (int q = 0; q < 4; ++q) {
        f32x2 t;
        t.x = __uint_as_float(u[q] << 16);
        t.y = __uint_as_float(u[q] & 0xffff0000u);
        a[q] += t;   // v_pk_add_f32
    }
}

__global__ __launch_bounds__(256) void gather_cb(
    const unsigned short* __restrict__ h, size_t h_zstride,
    const float* __restrict__ normp,
    const int* __restrict__ row_ptr, const unsigned* __restrict__ edge_pack,
    unsigned short* __restrict__ agg, size_t a_zstride, int nwu) {
    const int k = blockIdx.x & 7;
    const int bi = blockIdx.x >> 3;
    const int start = (k * nwu) >> 3;
    const int end = ((k + 1) * nwu) >> 3;
    const int w = start + bi;
    if (w >= end) return;
    const int combo = w / BPC;
    const int j = w - combo * BPC;
    const int s = combo >> 2;   // NCB == 4
    const int cb = combo & 3;
    const int lane = threadIdx.x & 63, wave = threadIdx.x >> 6;
    const int grp = lane >> 3;          // 0..7: node within wave
    const int lc = lane & 7;            // lane within group
    const char* __restrict__ hbb =
        (const char*)h + ((size_t)s * h_zstride + cb * COLBLK + lc * 8) * 2;
    const int p = j * VPB + wave * 8 + grp;   // permuted node id
    const int beg = row_ptr[p], end_e = row_ptr[p + 1];
    const float nv = normp[p];
    const unsigned* __restrict__ ep = edge_pack + beg;
    const int n = end_e - beg;
    f32x2 a[4] = {};
    int i = 0;
    for (; i + 7 < n; i += 8) {
        unsigned e[8];
        uint4 r[8];
#pragma unroll
        for (int q = 0; q < 8; ++q) e[q] = ep[i + q];
#pragma unroll
        for (int q = 0; q < 8; ++q)
            r[q] = *reinterpret_cast<const uint4*>(hbb + e[q]);
#pragma unroll
        for (int q = 0; q < 8; ++q) accum8(a, r[q]);
    }
    for (; i + 3 < n; i += 4) {
        unsigned e[4];
        uint4 r[4];
#pragma unroll
        for (int q = 0; q < 4; ++q) e[q] = ep[i + q];
#pragma unroll
        for (int q = 0; q < 4; ++q)
            r[q] = *reinterpret_cast<const uint4*>(hbb + e[q]);
#pragma unroll
        for (int q = 0; q < 4; ++q) accum8(a, r[q]);
    }
    for (; i < n; ++i) {
        const uint4 r0 = *reinterpret_cast<const uint4*>(hbb + ep[i]);
        accum8(a, r0);
    }
    uint4 o;
    unsigned* ou = reinterpret_cast<unsigned*>(&o);
#pragma unroll
    for (int q = 0; q < 4; ++q) {
        unsigned lo = f2bf(nv * a[q].x);
        unsigned hi = f2bf(nv * a[q].y);
        ou[q] = lo | (hi << 16);
    }
    *reinterpret_cast<uint4*>(
        &agg[(size_t)s * a_zstride + (size_t)p * HIDDEN + cb * COLBLK + lc * 8]) = o;
}

// ---------------- MFMA GEMM: C[M_PAD x 256] = A[M_PAD x K] @ Bt^T ----------------
// optional BN+ReLU; optional rowscale (writes hn = normp ⊙ result for gather consumption)
template <int K, bool BNRELU, bool RS>
__global__ __launch_bounds__(256, 3) void mfma_gemm(
    const unsigned short* __restrict__ A, size_t a_zstride,
    const unsigned short* __restrict__ Bt, size_t b_zstride,
    unsigned short* __restrict__ C, size_t c_zstride,
    const float* __restrict__ bn_scale, const float* __restrict__ bn_shift, int bn_zstride,
    const float* __restrict__ rowscale) {
    constexpr int BK = 64;
    __shared__ __align__(16) unsigned short As[128 * BK];
    __shared__ __align__(16) unsigned short Bs[128 * BK];
    const int z = blockIdx.z;
    A += (size_t)z * a_zstride;
    Bt += (size_t)z * b_zstride;
    C += (size_t)z * c_zstride;
    const int tid = threadIdx.x, lane = tid & 63, wave = tid >> 6;
    const int wr = wave >> 1, wc = wave & 1;
    const int r0 = blockIdx.x * 128, c0 = blockIdx.y * 128;

    const int lrow = lane >> 3;
    const int kch = (lane & 7) ^ lrow;
    const int frow = lane & 15;
    const int kgrp = lane >> 4;

    f32x4 acc[4][4];
#pragma unroll
    for (int i = 0; i < 4; ++i)
#pragma unroll
        for (int j = 0; j < 4; ++j) acc[i][j] = (f32x4)0.f;

    int aoff[4][2], boff[4][2];
#pragma unroll
    for (int fm = 0; fm < 4; ++fm) {
        const int ra = wr * 64 + fm * 16 + frow;
        const int rb = wc * 64 + fm * 16 + frow;
#pragma unroll
        for (int ks = 0; ks < 2; ++ks) {
            aoff[fm][ks] = ra * 64 + ((ks * 4 + kgrp) ^ (ra & 7)) * 8;
            boff[fm][ks] = rb * 64 + ((ks * 4 + kgrp) ^ (rb & 7)) * 8;
        }
    }

    constexpr int NK = K / BK;
#pragma unroll
    for (int k0 = 0; k0 < NK; ++k0) {
        const int kk = k0 * BK;
#pragma unroll
        for (int i = 0; i < 4; ++i) {
            const int tb = wave * 32 + i * 8;
            load_lds16(&A[(size_t)(r0 + tb + lrow) * K + kk + kch * 8], &As[tb * 64]);
            load_lds16(&Bt[(size_t)(c0 + tb + lrow) * K + kk + kch * 8], &Bs[tb * 64]);
        }
        __syncthreads();
#pragma unroll
        for (int ks = 0; ks < 2; ++ks) {
            bf16x8 af[4], bfr[4];
#pragma unroll
            for (int fm = 0; fm < 4; ++fm) af[fm] = *reinterpret_cast<const bf16x8*>(&As[aoff[fm][ks]]);
#pragma unroll
            for (int fn = 0; fn < 4; ++fn) bfr[fn] = *reinterpret_cast<const bf16x8*>(&Bs[boff[fn][ks]]);
#pragma unroll
            for (int fm = 0; fm < 4; ++fm)
#pragma unroll
                for (int fn = 0; fn < 4; ++fn)
                    acc[fm][fn] = __builtin_amdgcn_mfma_f32_16x16x32_bf16(af[fm], bfr[fn], acc[fm][fn], 0, 0, 0);
        }
        __syncthreads();
    }

    float rsv[4][4];
    if (RS) {
#pragma unroll
        for (int fm = 0; fm < 4; ++fm) {
            const int rbase = r0 + wr * 64 + fm * 16 + kgrp * 4;
#pragma unroll
            for (int r = 0; r < 4; ++r) rsv[fm][r] = rowscale[rbase + r];
        }
    }

#pragma unroll
    for (int fn = 0; fn < 4; ++fn) {
        const int col = c0 + wc * 64 + fn * 16 + frow;
        float sc = 1.f, sh = 0.f;
        if (BNRELU) {
            sc = bn_scale[z * bn_zstride + col];
            sh = bn_shift[z * bn_zstride + col];
        }
#pragma unroll
        for (int fm = 0; fm < 4; ++fm) {
            const int rbase = r0 + wr * 64 + fm * 16 + kgrp * 4;
#pragma unroll
            for (int r = 0; r < 4; ++r) {
                float x = acc[fm][fn][r];
                if (BNRELU) x = fmaxf(x * sc + sh, 0.f);
                if (RS) x *= rsv[fm][r];
                C[(size_t)(rbase + r) * HIDDEN + col] = f2bf(x);
            }
        }
    }
}

// ---------------- per-graph mean pool (h rows in permuted order -> pinv lookup) ----------------
__global__ __launch_bounds__(256) void pool_kernel(
    const unsigned short* __restrict__ h, size_t h_zstride,
    const int* __restrict__ pinv,
    const int* __restrict__ gstart, float* __restrict__ pool, int s0) {
    const int g = blockIdx.x, c = threadIdx.x;
    const int s = s0 + blockIdx.y;
    const unsigned short* hb = h + (size_t)blockIdx.y * h_zstride;
    const int beg = gstart[g], end = gstart[g + 1];
    float acc = 0.f;
    for (int v = beg; v < end; ++v) {
        int p = pinv[v];
        acc += bf2f(hb[(size_t)p * HIDDEN + c]);
    }
    pool[((size_t)s * NUM_GRAPHS + g) * HIDDEN + c] = acc / fmaxf((float)(end - beg), 1.f);
}

// ---------------- final MLP ----------------
__global__ __launch_bounds__(256) void final_kernel(
    const float* __restrict__ pool,
    const float* __restrict__ W_fc1, const float* __restrict__ b_fc1,
    const float* __restrict__ W_out, const float* __restrict__ b_out,
    float* __restrict__ out) {
    __shared__ float hv[HIDDEN];
    __shared__ float h1[HIDDEN];
    __shared__ float red[HIDDEN];
    const int g = blockIdx.x, t = threadIdx.x;
    float x = 0.f;
#pragma unroll
    for (int s = 0; s < NUM_SCALES; ++s) x += pool[((size_t)s * NUM_GRAPHS + g) * HIDDEN + t];
    x *= (1.0f / NUM_SCALES);
    red[t] = x * x;
    __syncthreads();
    for (int off = 128; off > 0; off >>= 1) {
        if (t < off) red[t] += red[t + off];
        __syncthreads();
    }
    float inv = 1.0f / fmaxf(sqrtf(red[0]), 1e-12f);
    hv[t] = x * inv;
    __syncthreads();
    float acc = b_fc1[t];
    for (int k = 0; k < HIDDEN; ++k) acc += hv[k] * W_fc1[k * HIDDEN + t];
    h1[t] = (acc > 0.f) ? acc : 0.01f * acc;
    __syncthreads();
    if (t < OUT_DIM) {
        float o = b_out[t];
        for (int k = 0; k < HIDDEN; ++k) o += h1[k] * W_out[k * OUT_DIM + t];
        out[g * OUT_DIM + t] = 1.0f / (1.0f + expf(-o));
    }
}

extern "C" void kernel_launch(void* const* d_in, const int* in_sizes, int n_in,
                              void* d_out, int out_size, void* d_ws, size_t ws_size,
                              hipStream_t stream) {
    const float* features  = (const float*)d_in[0];
    const int*   src       = (const int*)d_in[1];
    const int*   dst       = (const int*)d_in[2];
    const int*   graph_ids = (const int*)d_in[3];
    const float* W_proj   = (const float*)d_in[5];
    const float* W_conv   = (const float*)d_in[6];
    const float* bn_gamma = (const float*)d_in[7];
    const float* bn_beta  = (const float*)d_in[8];
    const float* bn_mean  = (const float*)d_in[9];
    const float* bn_var   = (const float*)d_in[10];
    const float* W_fc1    = (const float*)d_in[11];
    const float* b_fc1    = (const float*)d_in[12];
    const float* W_out    = (const float*)d_in[13];
    const float* b_out    = (const float*)d_in[14];
    float* out = (float*)d_out;

    size_t off = 0;
    char* base = (char*)d_ws;
    auto alloc = [&](size_t bytes) -> void* {
        void* p = base + off;
        off += (bytes + 255) & ~(size_t)255;
        return p;
    };
    int*   cnt       = (int*)alloc(N_NODES * 4);
    float* normp     = (float*)alloc(N_NODES * 4);
    int*   row_ptr   = (int*)alloc((N_NODES + 1) * 4);
    int*   cursor    = (int*)alloc(N_NODES * 4);
    unsigned* edge_pack = (unsigned*)alloc((size_t)N_EDGES * 4);
    int*   gstart    = (int*)alloc((NUM_GRAPHS + 1) * 4);
    int*   dhist     = (int*)alloc(128 * 4);
    int*   bincur    = (int*)alloc(128 * 4);
    int*   perm      = (int*)alloc(N_NODES * 4);
    int*   pinv      = (int*)alloc(N_NODES * 4);
    int*   degp      = (int*)alloc(N_NODES * 4);
    float* bn_scale  = (float*)alloc(NUM_SCALES * NUM_CONVS * HIDDEN * 4);
    float* bn_shift  = (float*)alloc(NUM_SCALES * NUM_CONVS * HIDDEN * 4);
    unsigned short* feat_b  = (unsigned short*)alloc((size_t)M_PAD * IN_FEAT * 2);
    unsigned short* Wt_proj = (unsigned short*)alloc((size_t)NUM_SCALES * HIDDEN * IN_FEAT * 2);
    unsigned short* Wt_conv = (unsigned short*)alloc((size_t)NUM_SCALES * NUM_CONVS * HIDDEN * HIDDEN * 2);
    float* pool      = (float*)alloc((size_t)NUM_SCALES * NUM_GRAPHS * HIDDEN * 4);

    const size_t HSZ = (size_t)M_PAD * HIDDEN;
    const bool batched = (ws_size - off) >= (2 * NUM_SCALES * HSZ * 2 + 1024);
    const int nsb = batched ? NUM_SCALES : 1;
    unsigned short* h_all   = (unsigned short*)alloc((size_t)nsb * HSZ * 2);
    unsigned short* agg_all = (unsigned short*)alloc((size_t)nsb * HSZ * 2);

    // ---- setup: degrees, degree-sort perm, permuted CSR ----
    hipMemsetAsync(cnt, 0, N_NODES * sizeof(int), stream);
    hipMemsetAsync(dhist, 0, 256 * sizeof(int), stream);  // dhist + bincur (adjacent)
    hist_kernel<<<(N_EDGES + 255) / 256, 256, 0, stream>>>(dst, cnt);
    deg_hist_kernel<<<(N_NODES + 255) / 256, 256, 0, stream>>>(cnt, dhist);
    deg_place_kernel<<<(N_NODES + 255) / 256, 256, 0, stream>>>(cnt, dhist, bincur,
                                                                perm, degp, pinv);
    scanp_kernel<<<1, 1024, 0, stream>>>(degp, row_ptr, normp);
    hipMemsetAsync(cursor, 0, N_NODES * sizeof(int), stream);
    scatter_kernel<<<(N_EDGES + 255) / 256, 256, 0, stream>>>(
        src, dst, row_ptr, cursor, pinv, edge_pack);
    graph_start_kernel<<<(N_NODES + 255) / 256, 256, 0, stream>>>(graph_ids, gstart);
    bn_precompute<<<NUM_SCALES * NUM_CONVS, 256, 0, stream>>>(bn_gamma, bn_beta, bn_mean, bn_var,
                                                              bn_scale, bn_shift);
    feat_convert<<<(M_PAD * IN_FEAT / 4 + 255) / 256, 256, 0, stream>>>(features, perm, feat_b);
    transpose_bf16<<<dim3(IN_FEAT / 32, HIDDEN / 32, NUM_SCALES), dim3(32, 8), 0, stream>>>(
        W_proj, Wt_proj, IN_FEAT, HIDDEN);
    transpose_bf16<<<dim3(HIDDEN / 32, HIDDEN / 32, NUM_SCALES * NUM_CONVS), dim3(32, 8), 0, stream>>>(
        W_conv, Wt_conv, HIDDEN, HIDDEN);

    const int MT = M_PAD / 128;  // 157
    if (batched) {
        const int nwu = NUM_SCALES * NCB * BPC;              // 12500
        const int ggrid = 8 * ((nwu + 7) / 8);               // 12504
        // proj writes hn0 = normp ⊙ (feat @ Wproj)
        mfma_gemm<IN_FEAT, false, true><<<dim3(MT, 2, NUM_SCALES), 256, 0, stream>>>(
            feat_b, 0, Wt_proj, (size_t)HIDDEN * IN_FEAT, h_all, HSZ, nullptr, nullptr, 0, normp);
        for (int i = 0; i < NUM_CONVS; ++i) {
            gather_cb<<<ggrid, 256, 0, stream>>>(
                h_all, HSZ, normp, row_ptr, edge_pack, agg_all, HSZ, nwu);
            if (i < NUM_CONVS - 1) {
                mfma_gemm<HIDDEN, true, true><<<dim3(MT, 2, NUM_SCALES), 256, 0, stream>>>(
                    agg_all, HSZ, Wt_conv + (size_t)i * HIDDEN * HIDDEN, (size_t)NUM_CONVS * HIDDEN * HIDDEN,
                    h_all, HSZ, bn_scale + i * HIDDEN, bn_shift + i * HIDDEN, NUM_CONVS * HIDDEN, normp);
            } else {
                mfma_gemm<HIDDEN, true, false><<<dim3(MT, 2, NUM_SCALES), 256, 0, stream>>>(
                    agg_all, HSZ, Wt_conv + (size_t)i * HIDDEN * HIDDEN, (size_t)NUM_CONVS * HIDDEN * HIDDEN,
                    h_all, HSZ, bn_scale + i * HIDDEN, bn_shift + i * HIDDEN, NUM_CONVS * HIDDEN, nullptr);
            }
        }
        pool_kernel<<<dim3(NUM_GRAPHS, NUM_SCALES), 256, 0, stream>>>(
            h_all, HSZ, pinv, gstart, pool, 0);
    } else {
        const int nwu = NCB * BPC;                           // 2500
        const int ggrid = 8 * ((nwu + 7) / 8);
        for (int s = 0; s < NUM_SCALES; ++s) {
            mfma_gemm<IN_FEAT, false, true><<<dim3(MT, 2, 1), 256, 0, stream>>>(
                feat_b, 0, Wt_proj + (size_t)s * HIDDEN * IN_FEAT, 0, h_all, 0, nullptr, nullptr, 0, normp);
            for (int i = 0; i < NUM_CONVS; ++i) {
                const size_t li = (size_t)(s * NUM_CONVS + i);
                gather_cb<<<ggrid, 256, 0, stream>>>(
                    h_all, 0, normp, row_ptr, edge_pack, agg_all, 0, nwu);
                if (i < NUM_CONVS - 1) {
                    mfma_gemm<HIDDEN, true, true><<<dim3(MT, 2, 1), 256, 0, stream>>>(
                        agg_all, 0, Wt_conv + li * HIDDEN * HIDDEN, 0, h_all, 0,
                        bn_scale + li * HIDDEN, bn_shift + li * HIDDEN, 0, normp);
                } else {
                    mfma_gemm<HIDDEN, true, false><<<dim3(MT, 2, 1), 256, 0, stream>>>(
                        agg_all, 0, Wt_conv + li * HIDDEN * HIDDEN, 0, h_all, 0,
                        bn_scale + li * HIDDEN, bn_shift + li * HIDDEN, 0, nullptr);
                }
            }
            pool_kernel<<<dim3(NUM_GRAPHS, 1), 256, 0, stream>>>(
                h_all, 0, pinv, gstart, pool, s);
        }
    }
    final_kernel<<<NUM_GRAPHS, 256, 0, stream>>>(pool, W_fc1, b_fc1, W_out, b_out, out);
}